// Round 1
// baseline (129711.926 us; speedup 1.0000x reference)
//
#include <hip/hip_runtime.h>

// LSTM, B=64 T=512 I=512 H=1024, fp32 exact baseline.
// Design: single persistent kernel, 256 blocks x 256 threads (1 block/CU).
//  - Block k owns h-indices j in [4k,4k+4) for ALL 64 batch rows (batch in lanes
//    => 64x reuse of every W element, W stays wave-uniform => SMEM s_load).
//  - Wave p (p = tid>>6, readfirstlane-scalarized) takes K-quarter p of the fused
//    K = I + H = 1536 dot; 16 fp32 accumulators/thread (4 gates x 4 j).
//  - Cross-wave K-reduction via padded LDS each step; wave p then owns the
//    c/h update for j = 4k+p (c lives in a register across all 512 steps).
//  - h double-buffered in ws, stored TRANSPOSED [j][b] so writes and next-step
//    activation reads are both lane-coalesced. x pre-transposed once to [t][i][b].
//  - One custom device-scope tree barrier per step (16x16 -> root -> gen).

#define BB 64
#define TT 512
#define II 512
#define HH 1024

#define NBLK 256
#define NTHR 256

// ws layout (bytes):
//   [0, 8192)                      barrier state: gen@int[0], root@int[64], cnt[g]@int[128+64*g]
//   [8192, 8192+2*HH*BB*4)         hbuf[2][HH][BB] fp32   (512 KiB)
//   [1<<20, 1<<20 + TT*II*BB*4)    xT[TT][II][BB]  fp32   (64 MiB)
#define WS_SYNC_OFF 0
#define WS_HBUF_OFF 8192
#define WS_XT_OFF   (1 << 20)

__device__ __forceinline__ void grid_barrier(int* syncp)
{
    __syncthreads();
    if (threadIdx.x == 0) {
        int* gen  = syncp;
        int* root = syncp + 64;
        int* cnt  = syncp + 128;
        const int g = __hip_atomic_load(gen, __ATOMIC_RELAXED, __HIP_MEMORY_SCOPE_AGENT);
        __threadfence();  // order this block's h-stores before the arrival add
        const int grp = (int)(blockIdx.x >> 4);  // 16 groups of 16 blocks
        bool last = false;
        const int a1 = __hip_atomic_fetch_add(&cnt[grp * 64], 1,
                                              __ATOMIC_ACQ_REL, __HIP_MEMORY_SCOPE_AGENT);
        if (a1 == 15) {  // group complete -> arrive at root
            const int a2 = __hip_atomic_fetch_add(root, 1,
                                                  __ATOMIC_ACQ_REL, __HIP_MEMORY_SCOPE_AGENT);
            if (a2 == 15) {  // all 256 blocks arrived: reset, then release generation
                for (int q = 0; q < 16; ++q)
                    __hip_atomic_store(&cnt[q * 64], 0, __ATOMIC_RELAXED, __HIP_MEMORY_SCOPE_AGENT);
                __hip_atomic_store(root, 0, __ATOMIC_RELAXED, __HIP_MEMORY_SCOPE_AGENT);
                __hip_atomic_fetch_add(gen, 1, __ATOMIC_RELEASE, __HIP_MEMORY_SCOPE_AGENT);
                last = true;
            }
        }
        if (!last) {
            while (__hip_atomic_load(gen, __ATOMIC_RELAXED, __HIP_MEMORY_SCOPE_AGENT) == g)
                __builtin_amdgcn_s_sleep(2);
            __builtin_amdgcn_fence(__ATOMIC_ACQUIRE, "agent");  // make released h-stores visible
        }
    }
    __syncthreads();
}

// xT[t][i][b] = x[b][t][i] ; one 64(b) x 64(i) tile per block, t fixed.
__global__ void __launch_bounds__(256, 1)
transpose_x(const float* __restrict__ x, float* __restrict__ xT)
{
    __shared__ float tile[64][65];
    const int blk = (int)blockIdx.x;
    const int t   = blk >> 3;
    const int i0  = (blk & 7) << 6;
    const int tid = (int)threadIdx.x;
    const int li  = tid & 63;
    const int q   = tid >> 6;
#pragma unroll
    for (int r = 0; r < 16; ++r) {
        const int bb = q * 16 + r;
        tile[bb][li] = x[(bb * TT + t) * II + i0 + li];  // lanes li: coalesced
    }
    __syncthreads();
#pragma unroll
    for (int r = 0; r < 16; ++r) {
        const int ii = q * 16 + r;
        xT[(t * II + i0 + ii) * BB + li] = tile[li][ii];  // lanes li(=b): coalesced
    }
}

__global__ void __launch_bounds__(NTHR, 1)
lstm_persist(const float* __restrict__ xT,
             const int*   __restrict__ lens,
             const float* __restrict__ Wih,   // [4H][I]
             const float* __restrict__ Whh,   // [4H][H]
             const float* __restrict__ bih,
             const float* __restrict__ bhh,
             float* __restrict__ hbuf,        // [2][H][B]
             int*   __restrict__ syncp,
             float* __restrict__ out)         // [B][H]
{
    const int tid = (int)threadIdx.x;
    const int b   = tid & 63;                                   // lane = batch row
    const int p   = __builtin_amdgcn_readfirstlane(tid >> 6);   // wave id, forced SGPR
    const int j0  = (int)blockIdx.x << 2;
    const int j   = j0 + p;                                     // this wave's update h-index

    __shared__ float red[4][64][17];  // +1 pad: 2-way bank aliasing only (free)

    // K-quarter for this wave over fused K = I(x-part) + H(h-part)
    const int ks = p * 384;
    const int ke = ks + 384;
    const int xs = ks;
    const int xe = (ke < II) ? ke : II;          // x-part [xs,xe)
    const int hs = (ks > II) ? (ks - II) : 0;    // h-part [hs,he)
    const int he = ke - II;

    float bias[4];
#pragma unroll
    for (int g = 0; g < 4; ++g)
        bias[g] = bih[g * HH + j] + bhh[g * HH + j];

    const int len = lens[b];

    // init h_0 = 0 (each (j,b) has exactly one owner across the grid)
    hbuf[j * BB + b] = 0.0f;
    if (len == 0) out[b * HH + j] = 0.0f;  // lengths==0 -> zero output

    float c = 0.0f;

    grid_barrier(syncp);  // h_0 fully initialized everywhere

    for (int t = 0; t < TT; ++t) {
        float acc[16];
#pragma unroll
        for (int a = 0; a < 16; ++a) acc[a] = 0.0f;

        // ---- x-part: gates += W_ih[row][k] * x_t[k][b] ----
        const float* __restrict__ ax = xT + t * (II * BB);
        for (int k = xs; k < xe; ++k) {
            const float a = ax[k * BB + b];  // coalesced, L1/L2-resident
#pragma unroll
            for (int g = 0; g < 4; ++g)
#pragma unroll
                for (int jj = 0; jj < 4; ++jj)
                    acc[g * 4 + jj] = fmaf(Wih[(g * HH + j0 + jj) * II + k], a, acc[g * 4 + jj]);
        }
        // ---- h-part: gates += W_hh[row][k] * h_t[k][b] ----
        const float* __restrict__ ah = hbuf + (t & 1) * (HH * BB);
        for (int k = hs; k < he; ++k) {
            const float a = ah[k * BB + b];
#pragma unroll
            for (int g = 0; g < 4; ++g)
#pragma unroll
                for (int jj = 0; jj < 4; ++jj)
                    acc[g * 4 + jj] = fmaf(Whh[(g * HH + j0 + jj) * HH + k], a, acc[g * 4 + jj]);
        }

        // ---- cross-wave K reduction through LDS ----
#pragma unroll
        for (int a = 0; a < 16; ++a) red[p][b][a] = acc[a];
        __syncthreads();

        float gate[4];
#pragma unroll
        for (int g = 0; g < 4; ++g)
            gate[g] = bias[g]
                    + red[0][b][g * 4 + p] + red[1][b][g * 4 + p]
                    + red[2][b][g * 4 + p] + red[3][b][g * 4 + p];

        // PyTorch gate order i,f,g,o
        const float ig = 1.0f / (1.0f + __expf(-gate[0]));
        const float fg = 1.0f / (1.0f + __expf(-gate[1]));
        const float gg = tanhf(gate[2]);
        const float og = 1.0f / (1.0f + __expf(-gate[3]));
        c = fg * c + ig * gg;
        const float h = og * tanhf(c);

        hbuf[((t + 1) & 1) * (HH * BB) + j * BB + b] = h;  // coalesced in b
        if (t == len - 1) out[b * HH + j] = h;             // last valid hidden

        grid_barrier(syncp);  // also protects `red` reuse next step
    }
}

extern "C" void kernel_launch(void* const* d_in, const int* in_sizes, int n_in,
                              void* d_out, int out_size, void* d_ws, size_t ws_size,
                              hipStream_t stream)
{
    const float* seq  = (const float*)d_in[0];
    const int*   lens = (const int*)  d_in[1];
    const float* Wih  = (const float*)d_in[2];
    const float* Whh  = (const float*)d_in[3];
    const float* bih  = (const float*)d_in[4];
    const float* bhh  = (const float*)d_in[5];
    float* out = (float*)d_out;

    char*  ws    = (char*)d_ws;
    int*   syncp = (int*)  (ws + WS_SYNC_OFF);
    float* hbuf  = (float*)(ws + WS_HBUF_OFF);
    float* xT    = (float*)(ws + WS_XT_OFF);

    // barrier state must be zero every call (ws is poisoned 0xAA by the harness)
    hipMemsetAsync(syncp, 0, 8192, stream);
    transpose_x<<<dim3(TT * (II / 64)), dim3(256), 0, stream>>>(seq, xT);
    lstm_persist<<<dim3(NBLK), dim3(NTHR), 0, stream>>>(xT, lens, Wih, Whh, bih, bhh,
                                                        hbuf, syncp, out);
}

// Round 2
// 33392.035 us; speedup vs baseline: 3.8845x; 3.8845x over previous
//
#include <hip/hip_runtime.h>
#include <hip/hip_bf16.h>

// LSTM B=64 T=512 I=512 H=1024, fp32.
// Round 2: (1) x-projection precomputed by a TLP-rich GEMM into gx[t][row][b]
// (removes 1/3 of sequential K); (2) recurrent persistent kernel keeps 8 of its
// 16 W_hh rows in LDS (ds_read_b128 broadcast) + 8 via s_load_dwordx4, 8 waves/
// block (2/SIMD), k-loop unrolled 4x2 => latency actually hidden; (3) two-phase
// LDS reduction keeps static LDS < 64KB.

#define BB 64
#define TT 512
#define II 512
#define HH 1024
#define NROW 4096           // 4*HH

#define NBLK 256
#define NTHR 512            // 8 waves

// ws layout
#define WS_SYNC_OFF 0                    // 8 KB barrier state
#define WS_HBUF_OFF 8192                 // hbuf[2][HH][BB] fp32, 512 KB
#define WS_BIG_OFF  (1 << 20)            // gx (mode0/1) or xT (mode2)
#define GX_F32_BYTES  ((size_t)TT * NROW * BB * 4)   // 512 MB
#define GX_BF16_BYTES ((size_t)TT * NROW * BB * 2)   // 256 MB
#define XT_BYTES      ((size_t)TT * II * BB * 4)     // 64 MB

__device__ __forceinline__ void grid_barrier(int* syncp)
{
    __syncthreads();
    if (threadIdx.x == 0) {
        int* gen  = syncp;
        int* root = syncp + 64;
        int* cnt  = syncp + 128;
        const int g = __hip_atomic_load(gen, __ATOMIC_RELAXED, __HIP_MEMORY_SCOPE_AGENT);
        __threadfence();
        const int grp = (int)(blockIdx.x >> 4);
        bool last = false;
        const int a1 = __hip_atomic_fetch_add(&cnt[grp * 64], 1,
                                              __ATOMIC_ACQ_REL, __HIP_MEMORY_SCOPE_AGENT);
        if (a1 == 15) {
            const int a2 = __hip_atomic_fetch_add(root, 1,
                                                  __ATOMIC_ACQ_REL, __HIP_MEMORY_SCOPE_AGENT);
            if (a2 == 15) {
                for (int q = 0; q < 16; ++q)
                    __hip_atomic_store(&cnt[q * 64], 0, __ATOMIC_RELAXED, __HIP_MEMORY_SCOPE_AGENT);
                __hip_atomic_store(root, 0, __ATOMIC_RELAXED, __HIP_MEMORY_SCOPE_AGENT);
                __hip_atomic_fetch_add(gen, 1, __ATOMIC_RELEASE, __HIP_MEMORY_SCOPE_AGENT);
                last = true;
            }
        }
        if (!last) {
            while (__hip_atomic_load(gen, __ATOMIC_RELAXED, __HIP_MEMORY_SCOPE_AGENT) == g)
                __builtin_amdgcn_s_sleep(2);
            __builtin_amdgcn_fence(__ATOMIC_ACQUIRE, "agent");
        }
    }
    __syncthreads();
}

__device__ __forceinline__ float fast_sigmoid(float x)
{
    return 1.0f / (1.0f + __expf(-x));
}
__device__ __forceinline__ float fast_tanh(float x)
{
    x = fminf(15.0f, fmaxf(-15.0f, x));
    const float e = __expf(2.0f * x);
    return (e - 1.0f) / (e + 1.0f);
}

// ---------------- gx = x @ Wih^T, gx[t][row][b] ----------------
// grid = T * 64 blocks, 256 thr (4 waves x 16 rows). x staged via swizzled LDS
// tile (conflict-free both sides): addr(i,b) = i*64 + ((b + (i>>2)) & 63).
template <typename GT>
__global__ void __launch_bounds__(256)
gx_gemm(const float* __restrict__ x, const float* __restrict__ Wih,
        GT* __restrict__ gx)
{
    __shared__ float tile[128 * 64];  // 32 KB
    const int blk = (int)blockIdx.x;
    const int t   = blk >> 6;
    const int rt  = blk & 63;
    const int tid = (int)threadIdx.x;
    const int b   = tid & 63;
    const int wp  = tid >> 6;
    const int row0 = rt * 64 + wp * 16;

    float acc[16];
#pragma unroll
    for (int r = 0; r < 16; ++r) acc[r] = 0.0f;

    const int g8 = tid >> 5;          // 0..7 (32-lane groups)
    const int c0 = (tid & 31) * 4;

    for (int ic = 0; ic < II; ic += 128) {
        __syncthreads();
#pragma unroll
        for (int r = 0; r < 8; ++r) {
            const int brow = g8 + r * 8;
            const float4 v = *(const float4*)(x + ((size_t)brow * TT + t) * II + ic + c0);
#pragma unroll
            for (int q = 0; q < 4; ++q) {
                const int i = c0 + q;
                tile[i * 64 + ((brow + (i >> 2)) & 63)] = ((const float*)&v)[q];
            }
        }
        __syncthreads();

#pragma unroll 2
        for (int i = 0; i < 128; i += 4) {
            float a4[4];
#pragma unroll
            for (int q = 0; q < 4; ++q)
                a4[q] = tile[(i + q) * 64 + ((b + ((i + q) >> 2)) & 63)];
#pragma unroll
            for (int r = 0; r < 16; ++r) {
                const float4 w = *(const float4*)(Wih + (size_t)(row0 + r) * II + ic + i);
                acc[r] = fmaf(w.x, a4[0], acc[r]);
                acc[r] = fmaf(w.y, a4[1], acc[r]);
                acc[r] = fmaf(w.z, a4[2], acc[r]);
                acc[r] = fmaf(w.w, a4[3], acc[r]);
            }
        }
    }
#pragma unroll
    for (int r = 0; r < 16; ++r) {
        const size_t off = ((size_t)t * NROW + row0 + r) * BB + b;
        if constexpr (sizeof(GT) == 4) gx[off] = acc[r];
        else                           gx[off] = (GT)acc[r];
    }
}

// xT[t][i][b] = x[b][t][i]  (mode-2 fallback only)
__global__ void __launch_bounds__(256)
transpose_x(const float* __restrict__ x, float* __restrict__ xT)
{
    __shared__ float tile[64][65];
    const int blk = (int)blockIdx.x;
    const int t   = blk >> 3;
    const int i0  = (blk & 7) << 6;
    const int tid = (int)threadIdx.x;
    const int li  = tid & 63;
    const int q   = tid >> 6;
#pragma unroll
    for (int r = 0; r < 16; ++r)
        tile[q * 16 + r][li] = x[((q * 16 + r) * TT + t) * II + i0 + li];
    __syncthreads();
#pragma unroll
    for (int r = 0; r < 16; ++r)
        xT[((size_t)t * II + i0 + q * 16 + r) * BB + li] = tile[li][q * 16 + r];
}

// ---------------- persistent recurrent kernel ----------------
// MODE: 0 = gx fp32, 1 = gx bf16, 2 = fused x via xT (fallback).
// Block: 512 thr (8 waves), owns 4 j's x 4 gates = 16 rows, all 64 b (lanes).
// Wave p covers k-range [p*KW, (p+1)*KW). Rows a < LDSROWS come from LDS
// (broadcast ds_read_b128), the rest via wave-uniform s_load_dwordx4.
template <int MODE>
__global__ void __launch_bounds__(NTHR, 1)
lstm_persist(const void*  __restrict__ gx_or_xT,
             const int*   __restrict__ lens,
             const float* __restrict__ Wih,
             const float* __restrict__ Whh,
             const float* __restrict__ bih,
             const float* __restrict__ bhh,
             float* __restrict__ hbuf,
             int*   __restrict__ syncp,
             float* __restrict__ out)
{
    constexpr int KTOT    = (MODE == 2) ? (II + HH) : HH;
    constexpr int KW      = KTOT / 8;
    constexpr int LDSROWS = (MODE == 2) ? 4 : 8;

    __shared__ float Wlds[LDSROWS * KTOT];   // 32 KB (24 KB mode2)
    __shared__ float red[4][64][17];         // 17.4 KB

    const int tid = (int)threadIdx.x;
    const int b   = tid & 63;
    const int p   = __builtin_amdgcn_readfirstlane(tid >> 6);   // wave 0..7
    const int j0  = (int)blockIdx.x << 2;

    // ---- stage LDS-resident W rows (row index a = g*4+jj) ----
    for (int idx = tid; idx < LDSROWS * KTOT; idx += NTHR) {
        const int r = idx / KTOT, k = idx - r * KTOT;
        const int row = (r >> 2) * HH + j0 + (r & 3);
        float w;
        if (MODE == 2) w = (k < II) ? Wih[(size_t)row * II + k] : Whh[(size_t)row * HH + (k - II)];
        else           w = Whh[(size_t)row * HH + k];
        Wlds[idx] = w;
    }

    const int kbase = p * KW;
    const int len   = lens[b];

    float bias[4], c = 0.0f;
    if (p < 4) {
        const int j = j0 + p;
#pragma unroll
        for (int g = 0; g < 4; ++g)
            bias[g] = bih[g * HH + j] + bhh[g * HH + j];
        hbuf[j * BB + b] = 0.0f;                 // h_0 = 0 (buffer 0)
        if (len == 0) out[b * HH + j] = 0.0f;
    }

    grid_barrier(syncp);  // h_0 + Wlds visible everywhere

    const float* __restrict__ gxf = (const float*)gx_or_xT;
    const __hip_bfloat16* __restrict__ gxb = (const __hip_bfloat16*)gx_or_xT;
    const float* __restrict__ xT = (const float*)gx_or_xT;

    for (int t = 0; t < TT; ++t) {
        // prefetch this step's gx early (used only in phase 3)
        float gxv[4] = {0.f, 0.f, 0.f, 0.f};
        if (MODE != 2 && p < 4) {
            const int j = j0 + p;
#pragma unroll
            for (int g = 0; g < 4; ++g) {
                const size_t off = ((size_t)t * NROW + g * HH + j) * BB + b;
                gxv[g] = (MODE == 0) ? gxf[off] : (float)gxb[off];
            }
        }

        float acc[16];
#pragma unroll
        for (int a = 0; a < 16; ++a) acc[a] = 0.0f;

        const float* __restrict__ hb = hbuf + (t & 1) * (HH * BB);

#pragma unroll 2
        for (int kc = 0; kc < KW; kc += 4) {
            const int k = kbase + kc;
            // activations (4 coalesced vector loads)
            float a4[4];
#pragma unroll
            for (int q = 0; q < 4; ++q) {
                const int kk = k + q;
                if (MODE == 2)
                    a4[q] = (kk < II) ? xT[((size_t)t * II + kk) * BB + b]
                                      : hb[(kk - II) * BB + b];
                else
                    a4[q] = hb[kk * BB + b];
            }
            // weights: LDS rows (broadcast b128) + scalar rows (s_load_dwordx4)
#pragma unroll
            for (int r = 0; r < 16; ++r) {
                float4 w;
                if (r < LDSROWS) {
                    w = *(const float4*)&Wlds[r * KTOT + k];
                } else {
                    const int row = (r >> 2) * HH + j0 + (r & 3);
                    if (MODE == 2)
                        w = (k < II) ? *(const float4*)(Wih + (size_t)row * II + k)
                                     : *(const float4*)(Whh + (size_t)row * HH + (k - II));
                    else
                        w = *(const float4*)(Whh + (size_t)row * HH + k);
                }
                acc[r] = fmaf(w.x, a4[0], acc[r]);
                acc[r] = fmaf(w.y, a4[1], acc[r]);
                acc[r] = fmaf(w.z, a4[2], acc[r]);
                acc[r] = fmaf(w.w, a4[3], acc[r]);
            }
        }

        // ---- two-phase cross-wave reduction ----
        if (p >= 4) {
#pragma unroll
            for (int a = 0; a < 16; ++a) red[p - 4][b][a] = acc[a];
        }
        __syncthreads();
        if (p < 4) {
#pragma unroll
            for (int a = 0; a < 16; ++a) acc[a] += red[p][b][a];
#pragma unroll
            for (int a = 0; a < 16; ++a) red[p][b][a] = acc[a];
        }
        __syncthreads();

        if (p < 4) {
            const int j = j0 + p;
            float gate[4];
#pragma unroll
            for (int g = 0; g < 4; ++g)
                gate[g] = bias[g] + gxv[g]
                        + red[0][b][g * 4 + p] + red[1][b][g * 4 + p]
                        + red[2][b][g * 4 + p] + red[3][b][g * 4 + p];
            const float ig = fast_sigmoid(gate[0]);
            const float fg = fast_sigmoid(gate[1]);
            const float gg = fast_tanh(gate[2]);
            const float og = fast_sigmoid(gate[3]);
            c = fg * c + ig * gg;
            const float h = og * fast_tanh(c);
            hbuf[((t + 1) & 1) * (HH * BB) + j * BB + b] = h;
            if (t == len - 1) out[b * HH + j] = h;
        }

        grid_barrier(syncp);   // h step boundary; also protects `red` reuse
    }
}

extern "C" void kernel_launch(void* const* d_in, const int* in_sizes, int n_in,
                              void* d_out, int out_size, void* d_ws, size_t ws_size,
                              hipStream_t stream)
{
    const float* seq  = (const float*)d_in[0];
    const int*   lens = (const int*)  d_in[1];
    const float* Wih  = (const float*)d_in[2];
    const float* Whh  = (const float*)d_in[3];
    const float* bih  = (const float*)d_in[4];
    const float* bhh  = (const float*)d_in[5];
    float* out = (float*)d_out;

    char*  ws    = (char*)d_ws;
    int*   syncp = (int*)  (ws + WS_SYNC_OFF);
    float* hbuf  = (float*)(ws + WS_HBUF_OFF);
    void*  big   = (void*) (ws + WS_BIG_OFF);

    hipMemsetAsync(syncp, 0, 8192, stream);

    if (ws_size >= (size_t)WS_BIG_OFF + GX_F32_BYTES) {
        gx_gemm<float><<<dim3(TT * 64), dim3(256), 0, stream>>>(seq, Wih, (float*)big);
        lstm_persist<0><<<dim3(NBLK), dim3(NTHR), 0, stream>>>(big, lens, Wih, Whh, bih, bhh,
                                                               hbuf, syncp, out);
    } else if (ws_size >= (size_t)WS_BIG_OFF + GX_BF16_BYTES) {
        gx_gemm<__hip_bfloat16><<<dim3(TT * 64), dim3(256), 0, stream>>>(seq, Wih,
                                                                         (__hip_bfloat16*)big);
        lstm_persist<1><<<dim3(NBLK), dim3(NTHR), 0, stream>>>(big, lens, Wih, Whh, bih, bhh,
                                                               hbuf, syncp, out);
    } else {
        transpose_x<<<dim3(TT * (II / 64)), dim3(256), 0, stream>>>(seq, (float*)big);
        lstm_persist<2><<<dim3(NBLK), dim3(NTHR), 0, stream>>>(big, lens, Wih, Whh, bih, bhh,
                                                               hbuf, syncp, out);
    }
}

// Round 3
// 24257.043 us; speedup vs baseline: 5.3474x; 1.3766x over previous
//
#include <hip/hip_runtime.h>

// LSTM B=64 T=512 I=512 H=1024 fp32 — round 3.
// Persistent fused kernel: 512 blocks x 512 thr (2 blocks/CU, 16 waves/CU).
// Block owns 2 h-columns (j0=blockIdx*2) x 4 gates = 8 rows; batch in lanes.
// ALL weights in LDS (48KB/block, ds_read_b128 broadcast, imm offsets).
// Coherence: h stored via agent-relaxed atomic stores (sc0sc1 write-through,
// L2 never dirty -> no buffer_wbl2 ever); one acquire fence (buffer_inv) per
// wave per step; grid barrier = relaxed atomics on MONOTONIC counters.
// Barrier latency hidden: x-projection partials for step t+1 are computed
// between barrier-arrive and barrier-wait (xT is immutable -> stale-safe).

#define BB 64
#define TT 512
#define II 512
#define HH 1024

#define NBLK 512
#define NTHR 512            // 8 waves
#define KWX  (II / 8)       // 64 x-k per wave
#define KWH  (HH / 8)       // 128 h-k per wave

#define WS_SYNC_OFF 0                 // 8 KB barrier state (memset 0 each call)
#define WS_HBUF_OFF 8192              // hbuf[2][HH][BB] fp32, 512 KB
#define WS_XT_OFF   (1 << 20)         // xT[TT][II][BB] fp32, 64 MB

__device__ __forceinline__ int atomic_add_rlx(int* p) {
    return __hip_atomic_fetch_add(p, 1, __ATOMIC_RELAXED, __HIP_MEMORY_SCOPE_AGENT);
}
__device__ __forceinline__ int load_rlx(int* p) {
    return __hip_atomic_load(p, __ATOMIC_RELAXED, __HIP_MEMORY_SCOPE_AGENT);
}
__device__ __forceinline__ void store_wt(float* p, float v) {   // write-through, no dirty L2
    __hip_atomic_store(p, v, __ATOMIC_RELAXED, __HIP_MEMORY_SCOPE_AGENT);
}

__device__ __forceinline__ float fast_sigmoid(float x) {
    return 1.0f / (1.0f + __expf(-x));
}
__device__ __forceinline__ float fast_tanh(float x) {
    x = fminf(15.0f, fmaxf(-15.0f, x));
    const float e = __expf(2.0f * x);
    return (e - 1.0f) / (e + 1.0f);
}

// Monotonic-counter tree barrier: 16 groups x 32 blocks. s is 1-based.
__device__ __forceinline__ void bar_arrive(int* syncp, int s)
{
    int* gen  = syncp;
    int* root = syncp + 64;
    int* cnt  = syncp + 128;
    const int grp = (int)(blockIdx.x >> 5);
    const int a1 = atomic_add_rlx(&cnt[grp * 64]);
    if (a1 == 32 * s - 1) {                 // group complete
        const int a2 = atomic_add_rlx(root);
        if (a2 == 16 * s - 1)               // all 512 arrived
            (void)atomic_add_rlx(gen);
    }
}
__device__ __forceinline__ void bar_wait(int* syncp, int s)
{
    int* gen = syncp;
    while (load_rlx(gen) < s)
        __builtin_amdgcn_s_sleep(2);
}

// xT[t][i][b] = x[b][t][i]
__global__ void __launch_bounds__(256)
transpose_x(const float* __restrict__ x, float* __restrict__ xT)
{
    __shared__ float tile[64][65];
    const int blk = (int)blockIdx.x;
    const int t   = blk >> 3;
    const int i0  = (blk & 7) << 6;
    const int tid = (int)threadIdx.x;
    const int li  = tid & 63;
    const int q   = tid >> 6;
#pragma unroll
    for (int r = 0; r < 16; ++r)
        tile[q * 16 + r][li] = x[((q * 16 + r) * TT + t) * II + i0 + li];
    __syncthreads();
#pragma unroll
    for (int r = 0; r < 16; ++r)
        xT[((size_t)t * II + i0 + q * 16 + r) * BB + li] = tile[li][q * 16 + r];
}

__global__ void __launch_bounds__(NTHR, 4)   // 4 waves/EU => 2 blocks/CU, VGPR<=128
lstm_persist(const float* __restrict__ xT,
             const int*   __restrict__ lens,
             const float* __restrict__ Wih,   // [4H][I]
             const float* __restrict__ Whh,   // [4H][H]
             const float* __restrict__ bih,
             const float* __restrict__ bhh,
             float* __restrict__ hbuf,        // [2][H][B]
             int*   __restrict__ syncp,
             float* __restrict__ out)         // [B][H]
{
    __shared__ float Wx[8][II];      // 16 KB
    __shared__ float Wh[8][HH];      // 32 KB
    __shared__ float red[4][BB][9];  // 9.2 KB (pad 9: 2-way banks = free)

    const int tid = (int)threadIdx.x;
    const int b   = tid & 63;
    const int p   = __builtin_amdgcn_readfirstlane(tid >> 6);   // wave 0..7
    const int j0  = (int)blockIdx.x << 1;                        // 2 j per block

    // ---- stage all 8 weight rows into LDS (row a = g*2+jj) ----
#pragma unroll
    for (int it = 0; it < 8; ++it) {                       // Wx: 8*512
        const int idx = tid + it * NTHR;
        const int a = idx >> 9, k = idx & 511;
        Wx[a][k] = Wih[(size_t)((a >> 1) * HH + j0 + (a & 1)) * II + k];
    }
#pragma unroll
    for (int it = 0; it < 16; ++it) {                      // Wh: 8*1024
        const int idx = tid + it * NTHR;
        const int a = idx >> 10, k = idx & 1023;
        Wh[a][k] = Whh[(size_t)((a >> 1) * HH + j0 + (a & 1)) * HH + k];
    }

    const int len = lens[b];
    float bias[4], c = 0.0f, lasth = 0.0f;
    if (p < 2) {
        const int j = j0 + p;
#pragma unroll
        for (int g = 0; g < 4; ++g)
            bias[g] = bih[g * HH + j] + bhh[g * HH + j];
        store_wt(&hbuf[j * BB + b], 0.0f);                 // h_0 = 0 (write-through)
    }

    int bar = 1;
    __syncthreads();                                       // stores + LDS staging done
    if (tid == 0) bar_arrive(syncp, bar);

    // ---- x-projection partials for t = 0 (overlaps barrier) ----
    float accx[8];
#pragma unroll
    for (int a = 0; a < 8; ++a) accx[a] = 0.0f;
    {
        const float* __restrict__ xb = xT + ((size_t)0 * II + p * KWX) * BB + b;
#pragma unroll
        for (int cx = 0; cx < KWX / 4; ++cx) {
            const int k = p * KWX + cx * 4;
            float a4[4];
#pragma unroll
            for (int q = 0; q < 4; ++q) a4[q] = xb[(cx * 4 + q) * BB];
#pragma unroll
            for (int r = 0; r < 8; ++r) {
                const float4 w = *(const float4*)&Wx[r][k];
                accx[r] = fmaf(w.x, a4[0], accx[r]);
                accx[r] = fmaf(w.y, a4[1], accx[r]);
                accx[r] = fmaf(w.z, a4[2], accx[r]);
                accx[r] = fmaf(w.w, a4[3], accx[r]);
            }
        }
    }

    if (tid == 0) bar_wait(syncp, bar);
    __syncthreads();
    __builtin_amdgcn_fence(__ATOMIC_ACQUIRE, "agent");     // buffer_inv (no wbl2)

    for (int t = 0; t < TT; ++t) {
        // ---- h-part: acc = accx + Whh-slice . h_t ----
        float acc[8];
#pragma unroll
        for (int a = 0; a < 8; ++a) acc[a] = accx[a];

        const float* __restrict__ hb =
            hbuf + (t & 1) * (HH * BB) + p * KWH * BB + b;
#pragma unroll 8
        for (int ch = 0; ch < KWH / 4; ++ch) {
            const int k = p * KWH + ch * 4;
            float a4[4];
#pragma unroll
            for (int q = 0; q < 4; ++q) a4[q] = hb[(ch * 4 + q) * BB];
#pragma unroll
            for (int r = 0; r < 8; ++r) {
                const float4 w = *(const float4*)&Wh[r][k];
                acc[r] = fmaf(w.x, a4[0], acc[r]);
                acc[r] = fmaf(w.y, a4[1], acc[r]);
                acc[r] = fmaf(w.z, a4[2], acc[r]);
                acc[r] = fmaf(w.w, a4[3], acc[r]);
            }
        }

        // ---- cross-wave reduction (8 -> 4 -> gate) ----
        if (p >= 4) {
#pragma unroll
            for (int a = 0; a < 8; ++a) red[p - 4][b][a] = acc[a];
        }
        __syncthreads();
        if (p < 4) {
#pragma unroll
            for (int a = 0; a < 8; ++a) red[p][b][a] += acc[a];
        }
        __syncthreads();

        // ---- gate math + h-update (waves 0,1) ----
        if (p < 2) {
            const int j = j0 + p;
            float gate[4];
#pragma unroll
            for (int g = 0; g < 4; ++g)
                gate[g] = bias[g]
                        + red[0][b][g * 2 + p] + red[1][b][g * 2 + p]
                        + red[2][b][g * 2 + p] + red[3][b][g * 2 + p];
            const float ig = fast_sigmoid(gate[0]);
            const float fg = fast_sigmoid(gate[1]);
            const float gg = fast_tanh(gate[2]);
            const float og = fast_sigmoid(gate[3]);
            c = fg * c + ig * gg;
            const float h = og * fast_tanh(c);
            store_wt(&hbuf[((t + 1) & 1) * (HH * BB) + j * BB + b], h);
            if (t == len - 1) lasth = h;
        }

        // ---- barrier, overlapped with x-partials for step t+1 ----
        ++bar;
        __syncthreads();                  // h stores complete (vmcnt 0)
        if (tid == 0) bar_arrive(syncp, bar);

#pragma unroll
        for (int a = 0; a < 8; ++a) accx[a] = 0.0f;
        if (t + 1 < TT) {
            const float* __restrict__ xb =
                xT + ((size_t)(t + 1) * II + p * KWX) * BB + b;
#pragma unroll
            for (int cx = 0; cx < KWX / 4; ++cx) {
                const int k = p * KWX + cx * 4;
                float a4[4];
#pragma unroll
                for (int q = 0; q < 4; ++q) a4[q] = xb[(cx * 4 + q) * BB];
#pragma unroll
                for (int r = 0; r < 8; ++r) {
                    const float4 w = *(const float4*)&Wx[r][k];
                    accx[r] = fmaf(w.x, a4[0], accx[r]);
                    accx[r] = fmaf(w.y, a4[1], accx[r]);
                    accx[r] = fmaf(w.z, a4[2], accx[r]);
                    accx[r] = fmaf(w.w, a4[3], accx[r]);
                }
            }
        }

        if (tid == 0) bar_wait(syncp, bar);
        __syncthreads();
        __builtin_amdgcn_fence(__ATOMIC_ACQUIRE, "agent");  // buffer_inv per wave
    }

    // ---- epilogue: last valid hidden (normal stores; nothing invalidates after) ----
    if (p < 2)
        out[b * HH + j0 + p] = lasth;
}

extern "C" void kernel_launch(void* const* d_in, const int* in_sizes, int n_in,
                              void* d_out, int out_size, void* d_ws, size_t ws_size,
                              hipStream_t stream)
{
    const float* seq  = (const float*)d_in[0];
    const int*   lens = (const int*)  d_in[1];
    const float* Wih  = (const float*)d_in[2];
    const float* Whh  = (const float*)d_in[3];
    const float* bih  = (const float*)d_in[4];
    const float* bhh  = (const float*)d_in[5];
    float* out = (float*)d_out;

    char*  ws    = (char*)d_ws;
    int*   syncp = (int*)  (ws + WS_SYNC_OFF);
    float* hbuf  = (float*)(ws + WS_HBUF_OFF);
    float* xT    = (float*)(ws + WS_XT_OFF);

    hipMemsetAsync(syncp, 0, 8192, stream);   // monotonic counters start at 0
    transpose_x<<<dim3(TT * (II / 64)), dim3(256), 0, stream>>>(seq, xT);
    lstm_persist<<<dim3(NBLK), dim3(NTHR), 0, stream>>>(xT, lens, Wih, Whh, bih, bhh,
                                                        hbuf, syncp, out);
}

// Round 4
// 13431.891 us; speedup vs baseline: 9.6570x; 1.8059x over previous
//
#include <hip/hip_runtime.h>

// LSTM B=64 T=512 I=512 H=1024 — round 4: MFMA with register-resident weights.
// Round-3 diagnosis: weight-broadcast-from-LDS is LDS-pipe-bound (6144
// ds_read_b128/CU/step ~= 30us vs 5us FMA). Fix: weights live in VGPRs as
// bf16 hi/lo A-fragments for the whole kernel; compute via 3-product
// split-bf16 MFMA (Whi*ahi + Whi*alo + Wlo*ahi ~ fp32 accuracy).
//   grid 256 = (128 j-tiles of 8) x (2 batch-halves of 32); 1 block/CU.
//   block: D[32 rows][32 b]; rows r = jj*4+g  => D quad=jj, reg=g: gate math
//   needs NO cross-lane transpose. waves = 2 m-tiles x 4 k-splits (384 k =>
//   12 tiles x {hi,lo} = 96 VGPR of weights/thread).
//   activations packed (bf16hi<<16)|bf16lo in uint32, layout [b][k] so B-frags
//   load as 2x dwordx4; x pre-packed to xpak[t][b][512]; h double-buffered
//   hpak[2][b][1024] via write-through atomic stores (no L2 dirty lines).
//   Cross-wave k-reduction: 3-syncthreads LDS tree (8 KB). Monotonic-counter
//   grid barrier + per-step agent-acquire (round-3 machinery, 16x16 groups).
//   x-part MFMAs for t+1 run between barrier arrive and wait (xpak immutable).

typedef short bf16x8 __attribute__((ext_vector_type(8)));
typedef float f32x4  __attribute__((ext_vector_type(4)));

#define BB 64
#define TT 512
#define II 512
#define HH 1024

#define NBLK 256
#define NTHR 512

#define WS_SYNC_OFF 0                 // 8 KB barrier state (memset 0 per call)
#define WS_HPAK_OFF 8192              // hpak[2][64][1024] u32 = 512 KB
#define WS_XPAK_OFF (1 << 20)         // xpak[512][64][512] u32 = 64 MB

__device__ __forceinline__ int atomic_add_rlx(int* p) {
    return __hip_atomic_fetch_add(p, 1, __ATOMIC_RELAXED, __HIP_MEMORY_SCOPE_AGENT);
}
__device__ __forceinline__ int load_rlx(int* p) {
    return __hip_atomic_load(p, __ATOMIC_RELAXED, __HIP_MEMORY_SCOPE_AGENT);
}
__device__ __forceinline__ void store_wt_u32(unsigned* p, unsigned v) {
    __hip_atomic_store(p, v, __ATOMIC_RELAXED, __HIP_MEMORY_SCOPE_AGENT);
}

// Monotonic tree barrier: 16 groups x 16 blocks, s is 1-based.
__device__ __forceinline__ void bar_arrive(int* syncp, int s)
{
    int* gen  = syncp;
    int* root = syncp + 64;
    int* cnt  = syncp + 128;
    const int grp = (int)(blockIdx.x >> 4);
    const int a1 = atomic_add_rlx(&cnt[grp * 64]);
    if (a1 == 16 * s - 1) {
        const int a2 = atomic_add_rlx(root);
        if (a2 == 16 * s - 1)
            (void)atomic_add_rlx(gen);
    }
}
__device__ __forceinline__ void bar_wait(int* syncp, int s)
{
    while (load_rlx(syncp) < s)
        __builtin_amdgcn_s_sleep(2);
}

__device__ __forceinline__ float fast_sigmoid(float x) {
    return 1.0f / (1.0f + __expf(-x));
}
__device__ __forceinline__ float fast_tanh(float x) {
    x = fminf(15.0f, fmaxf(-15.0f, x));
    const float e = __expf(2.0f * x);
    return (e - 1.0f) / (e + 1.0f);
}

// split fp32 -> bf16 hi + bf16 lo (RNE both), return bit patterns
__device__ __forceinline__ void split_bf16(float x, unsigned& hi, unsigned& lo)
{
    unsigned b = __float_as_uint(x);
    hi = (b + 0x7fffu + ((b >> 16) & 1u)) >> 16;
    float r = x - __uint_as_float(hi << 16);
    unsigned bl = __float_as_uint(r);
    lo = (bl + 0x7fffu + ((bl >> 16) & 1u)) >> 16;
}
__device__ __forceinline__ unsigned pack_hl(float x)
{
    unsigned hi, lo;
    split_bf16(x, hi, lo);
    return (hi << 16) | lo;
}

// unpack 8 consecutive packed words into hi/lo bf16x8 fragments
__device__ __forceinline__ void load_bfrag(const unsigned* base, bf16x8& bhi, bf16x8& blo)
{
    const uint4 a = *(const uint4*)base;
    const uint4 c = *(const uint4*)(base + 4);
    unsigned w[8] = {a.x, a.y, a.z, a.w, c.x, c.y, c.z, c.w};
#pragma unroll
    for (int j = 0; j < 8; ++j) {
        bhi[j] = (short)(w[j] >> 16);
        blo[j] = (short)(w[j] & 0xffffu);
    }
}

// xpak[t][b][i] = pack(x[b][t][i])
__global__ void __launch_bounds__(256)
transpose_pack_x(const float* __restrict__ x, unsigned* __restrict__ xpak)
{
    const int t   = (int)blockIdx.x;
    const int tid = (int)threadIdx.x;
#pragma unroll
    for (int rep = 0; rep < 8; ++rep) {
        const int f  = rep * 256 + tid;       // 0..2047
        const int b  = f >> 5;
        const int ch = (f & 31) * 16;         // 16 floats per unit
        const float* src = x + ((size_t)b * TT + t) * II + ch;
        unsigned* dst = xpak + ((size_t)t * BB + b) * II + ch;
        uint4 o[4];
#pragma unroll
        for (int v = 0; v < 4; ++v) {
            const float4 xv = *(const float4*)(src + v * 4);
            o[v].x = pack_hl(xv.x); o[v].y = pack_hl(xv.y);
            o[v].z = pack_hl(xv.z); o[v].w = pack_hl(xv.w);
        }
#pragma unroll
        for (int v = 0; v < 4; ++v)
            *(uint4*)(dst + v * 4) = o[v];
    }
}

__global__ void __launch_bounds__(NTHR, 2)   // 2 waves/EU -> <=256 VGPR, 1 block/CU
lstm_mfma(const unsigned* __restrict__ xpak,
          const int*   __restrict__ lens,
          const float* __restrict__ Wih,     // [4H][I]
          const float* __restrict__ Whh,     // [4H][H]
          const float* __restrict__ bih,
          const float* __restrict__ bhh,
          unsigned* __restrict__ hpak,       // [2][64][1024] packed
          int*   __restrict__ syncp,
          float* __restrict__ out)           // [B][H]
{
    __shared__ float red[2][2][2][16][16];   // [mt][slot][nt][bsub][r16] = 8 KB

    const int tid  = (int)threadIdx.x;
    const int l    = tid & 63;
    const int p    = __builtin_amdgcn_readfirstlane(tid >> 6);  // wave 0..7
    const int kh   = p & 3;                  // k-split 0..3
    const int mt   = p >> 2;                 // m-tile 0..1
    const int bsub = l & 15;
    const int q    = l >> 4;                 // quad

    const int jt = (int)blockIdx.x >> 1;
    const int bh = (int)blockIdx.x & 1;
    const int j0 = jt * 8;

    // ---- stage weight A-fragments into registers (persist across all t) ----
    // A-frag: m = lane&15 = r16, k = quad*8 + e.  r16 = jj_s*4 + g.
    const int jj_s = (l & 15) >> 2;
    const int g_r  = l & 3;
    const int row  = g_r * HH + j0 + mt * 4 + jj_s;

    bf16x8 whi[12], wlo[12];
#pragma unroll
    for (int kt = 0; kt < 12; ++kt) {
        const int ktg = (kt < 4) ? (4 * kh + kt) : (16 + 8 * kh + (kt - 4));
        const float* src = (ktg < 16)
            ? (Wih + (size_t)row * II + ktg * 32 + q * 8)
            : (Whh + (size_t)row * HH + (ktg - 16) * 32 + q * 8);
        const float4 w0 = *(const float4*)src;
        const float4 w1 = *(const float4*)(src + 4);
        const float wf[8] = {w0.x, w0.y, w0.z, w0.w, w1.x, w1.y, w1.z, w1.w};
#pragma unroll
        for (int e = 0; e < 8; ++e) {
            unsigned hi, lo;
            split_bf16(wf[e], hi, lo);
            whi[kt][e] = (short)hi;
            wlo[kt][e] = (short)lo;
        }
    }

    // ---- per-cell state (kh==0 waves own gate math: 2 cells/thread) ----
    float bias[4], c[2] = {0.f, 0.f}, lasth[2] = {0.f, 0.f};
    int len[2] = {0, 0};
    const int jcell = j0 + mt * 4 + q;       // this thread's j (kh0 waves)
    if (kh == 0) {
#pragma unroll
        for (int g = 0; g < 4; ++g)
            bias[g] = bih[g * HH + jcell] + bhh[g * HH + jcell];
#pragma unroll
        for (int nt = 0; nt < 2; ++nt) {
            const int b = bh * 32 + nt * 16 + bsub;
            len[nt] = lens[b];
            store_wt_u32(hpak + ((size_t)0 * BB + b) * HH + jcell, 0u);  // h_0 = 0
        }
    }

    int bar = 1;
    __syncthreads();                          // h_0 stores drained (vmcnt 0)
    if (tid == 0) bar_arrive(syncp, bar);

    // ---- x-part MFMAs for t=0 (overlap initial barrier) ----
    f32x4 acc[2];
#pragma unroll
    for (int nt = 0; nt < 2; ++nt) acc[nt] = (f32x4){0.f, 0.f, 0.f, 0.f};
    {
        const unsigned* x0 = xpak + (size_t)0 * BB * II;
#pragma unroll
        for (int xi = 0; xi < 4; ++xi) {
            const int ktg = 4 * kh + xi;
#pragma unroll
            for (int nt = 0; nt < 2; ++nt) {
                const int b = bh * 32 + nt * 16 + bsub;
                bf16x8 ahi, alo;
                load_bfrag(x0 + (size_t)b * II + ktg * 32 + q * 8, ahi, alo);
                acc[nt] = __builtin_amdgcn_mfma_f32_16x16x32_bf16(whi[xi], ahi, acc[nt], 0, 0, 0);
                acc[nt] = __builtin_amdgcn_mfma_f32_16x16x32_bf16(whi[xi], alo, acc[nt], 0, 0, 0);
                acc[nt] = __builtin_amdgcn_mfma_f32_16x16x32_bf16(wlo[xi], ahi, acc[nt], 0, 0, 0);
            }
        }
    }

    if (tid == 0) bar_wait(syncp, bar);
    __syncthreads();
    __builtin_amdgcn_fence(__ATOMIC_ACQUIRE, "agent");   // invalidate L1/L2

    for (int t = 0; t < TT; ++t) {
        // ---- h-part MFMAs: k = 256*kh + [0,256) of h ----
        const unsigned* hp = hpak + (size_t)(t & 1) * BB * HH;
#pragma unroll
        for (int hi2 = 0; hi2 < 8; ++hi2) {
            const int hk0 = 256 * kh + hi2 * 32;
#pragma unroll
            for (int nt = 0; nt < 2; ++nt) {
                const int b = bh * 32 + nt * 16 + bsub;
                bf16x8 ahi, alo;
                load_bfrag(hp + (size_t)b * HH + hk0 + q * 8, ahi, alo);
                acc[nt] = __builtin_amdgcn_mfma_f32_16x16x32_bf16(whi[4 + hi2], ahi, acc[nt], 0, 0, 0);
                acc[nt] = __builtin_amdgcn_mfma_f32_16x16x32_bf16(whi[4 + hi2], alo, acc[nt], 0, 0, 0);
                acc[nt] = __builtin_amdgcn_mfma_f32_16x16x32_bf16(wlo[4 + hi2], ahi, acc[nt], 0, 0, 0);
            }
        }

        // ---- cross-wave k-reduction: kh {2,3} -> {0,1}, then 1 -> 0 ----
        if (kh >= 2) {
#pragma unroll
            for (int nt = 0; nt < 2; ++nt)
                *(f32x4*)&red[mt][kh - 2][nt][bsub][4 * q] = acc[nt];
        }
        __syncthreads();
        if (kh < 2) {
#pragma unroll
            for (int nt = 0; nt < 2; ++nt)
                acc[nt] += *(f32x4*)&red[mt][kh][nt][bsub][4 * q];
        }
        __syncthreads();
        if (kh == 1) {
#pragma unroll
            for (int nt = 0; nt < 2; ++nt)
                *(f32x4*)&red[mt][0][nt][bsub][4 * q] = acc[nt];
        }
        __syncthreads();

        // ---- gate math on kh==0 waves (D: reg=gate, quad=jj -> in-register) ----
        if (kh == 0) {
#pragma unroll
            for (int nt = 0; nt < 2; ++nt) {
                const f32x4 r4 = *(f32x4*)&red[mt][0][nt][bsub][4 * q];
                const float ig = fast_sigmoid(acc[nt][0] + r4[0] + bias[0]);
                const float fg = fast_sigmoid(acc[nt][1] + r4[1] + bias[1]);
                const float gg = fast_tanh   (acc[nt][2] + r4[2] + bias[2]);
                const float og = fast_sigmoid(acc[nt][3] + r4[3] + bias[3]);
                c[nt] = fg * c[nt] + ig * gg;
                const float h = og * fast_tanh(c[nt]);
                const int b = bh * 32 + nt * 16 + bsub;
                store_wt_u32(hpak + ((size_t)((t + 1) & 1) * BB + b) * HH + jcell,
                             pack_hl(h));
                if (t == len[nt] - 1) lasth[nt] = h;
            }
        }

        // ---- grid barrier, overlapped with x-part MFMAs for t+1 ----
        ++bar;
        __syncthreads();                      // h stores drained before arrive
        if (tid == 0) bar_arrive(syncp, bar);

#pragma unroll
        for (int nt = 0; nt < 2; ++nt) acc[nt] = (f32x4){0.f, 0.f, 0.f, 0.f};
        if (t + 1 < TT) {
            const unsigned* xn = xpak + (size_t)(t + 1) * BB * II;
#pragma unroll
            for (int xi = 0; xi < 4; ++xi) {
                const int ktg = 4 * kh + xi;
#pragma unroll
                for (int nt = 0; nt < 2; ++nt) {
                    const int b = bh * 32 + nt * 16 + bsub;
                    bf16x8 ahi, alo;
                    load_bfrag(xn + (size_t)b * II + ktg * 32 + q * 8, ahi, alo);
                    acc[nt] = __builtin_amdgcn_mfma_f32_16x16x32_bf16(whi[xi], ahi, acc[nt], 0, 0, 0);
                    acc[nt] = __builtin_amdgcn_mfma_f32_16x16x32_bf16(whi[xi], alo, acc[nt], 0, 0, 0);
                    acc[nt] = __builtin_amdgcn_mfma_f32_16x16x32_bf16(wlo[xi], ahi, acc[nt], 0, 0, 0);
                }
            }
        }

        if (tid == 0) bar_wait(syncp, bar);
        __syncthreads();
        __builtin_amdgcn_fence(__ATOMIC_ACQUIRE, "agent");
    }

    // ---- epilogue: last valid hidden, fp32 ----
    if (kh == 0) {
#pragma unroll
        for (int nt = 0; nt < 2; ++nt) {
            const int b = bh * 32 + nt * 16 + bsub;
            out[(size_t)b * HH + jcell] = lasth[nt];
        }
    }
}

extern "C" void kernel_launch(void* const* d_in, const int* in_sizes, int n_in,
                              void* d_out, int out_size, void* d_ws, size_t ws_size,
                              hipStream_t stream)
{
    const float* seq  = (const float*)d_in[0];
    const int*   lens = (const int*)  d_in[1];
    const float* Wih  = (const float*)d_in[2];
    const float* Whh  = (const float*)d_in[3];
    const float* bih  = (const float*)d_in[4];
    const float* bhh  = (const float*)d_in[5];
    float* out = (float*)d_out;

    char*     ws    = (char*)d_ws;
    int*      syncp = (int*)     (ws + WS_SYNC_OFF);
    unsigned* hpak  = (unsigned*)(ws + WS_HPAK_OFF);
    unsigned* xpak  = (unsigned*)(ws + WS_XPAK_OFF);

    hipMemsetAsync(syncp, 0, 8192, stream);
    transpose_pack_x<<<dim3(TT), dim3(256), 0, stream>>>(seq, xpak);
    lstm_mfma<<<dim3(NBLK), dim3(NTHR), 0, stream>>>(xpak, lens, Wih, Whh, bih, bhh,
                                                     hpak, syncp, out);
}

// Round 5
// 11216.459 us; speedup vs baseline: 11.5644x; 1.1975x over previous
//
#include <hip/hip_runtime.h>

// LSTM B=64 T=512 I=512 H=1024 — round 5.
// Round-4 diagnosis: latency-bound on (a) 4KB-stride scattered h/x loads and
// 4B scattered write-through h stores, (b) 3-chained-RMW barrier release,
// (c) 8-way LDS bank conflicts in the reduction. MFMA/VALU both <5% busy.
// Fixes: fragment-native SPLIT-PLANE layout hi/lo u16 [k/8][b][k&7] --
// B-frags are single aligned b128 loads (no unpack), stores write-combine;
// flat monotonic barrier (no chained release); 3 independent MFMA acc
// streams; reduction pad 20.

typedef short bf16x8 __attribute__((ext_vector_type(8)));
typedef float f32x4  __attribute__((ext_vector_type(4)));

#define BB 64
#define TT 512
#define II 512
#define HH 1024

#define NBLK 256
#define NTHR 512

// ws layout (bytes)
#define WS_SYNC_OFF  0                       // barrier counter (memset 0 / call)
#define WS_HPAKH_OFF 8192                    // u16 [2][HH/8][BB][8] = 256 KB
#define WS_HPAKL_OFF (8192 + 262144)
#define WS_XPAKH_OFF (1 << 20)               // u16 [TT][II/8][BB][8] = 32 MB
#define WS_XPAKL_OFF ((1 << 20) + (32u << 20))

#define HBUF_STRIDE 65536                    // u16 per h buffer
#define XT_STRIDE   32768                    // u16 per timestep of x

__device__ __forceinline__ int atomic_add_rlx(int* p) {
    return __hip_atomic_fetch_add(p, 1, __ATOMIC_RELAXED, __HIP_MEMORY_SCOPE_AGENT);
}
__device__ __forceinline__ int load_rlx(int* p) {
    return __hip_atomic_load(p, __ATOMIC_RELAXED, __HIP_MEMORY_SCOPE_AGENT);
}
__device__ __forceinline__ void store_wt_u16(unsigned short* p, unsigned short v) {
    __hip_atomic_store(p, v, __ATOMIC_RELAXED, __HIP_MEMORY_SCOPE_AGENT);
}

__device__ __forceinline__ float fast_sigmoid(float x) {
    return 1.0f / (1.0f + __expf(-x));
}
__device__ __forceinline__ float fast_tanh(float x) {
    x = fminf(15.0f, fmaxf(-15.0f, x));
    const float e = __expf(2.0f * x);
    return (e - 1.0f) / (e + 1.0f);
}

// fp32 -> bf16 hi + bf16 lo-of-residual (RNE both)
__device__ __forceinline__ void split_bf16(float x, unsigned& hi, unsigned& lo)
{
    unsigned b = __float_as_uint(x);
    hi = (b + 0x7fffu + ((b >> 16) & 1u)) >> 16;
    float r = x - __uint_as_float(hi << 16);
    unsigned bl = __float_as_uint(r);
    lo = (bl + 0x7fffu + ((bl >> 16) & 1u)) >> 16;
}

#define MFMA(A, B, C) __builtin_amdgcn_mfma_f32_16x16x32_bf16((A), (B), (C), 0, 0, 0)

// x -> split planes, layout [t][k>>3][b][k&7] u16 per plane
__global__ void __launch_bounds__(256)
transpose_pack_x(const float* __restrict__ x,
                 unsigned short* __restrict__ xH, unsigned short* __restrict__ xL)
{
    __shared__ float tile[64][65];
    const int t   = (int)blockIdx.x;
    const int tid = (int)threadIdx.x;
    const int li  = tid & 63;
    const int w4  = tid >> 6;

    for (int kc = 0; kc < II; kc += 64) {
#pragma unroll
        for (int r = 0; r < 16; ++r) {
            const int b = w4 * 16 + r;
            tile[b][li] = x[((size_t)b * TT + t) * II + kc + li];   // coalesced
        }
        __syncthreads();
#pragma unroll
        for (int half = 0; half < 2; ++half) {
            const int u  = tid + half * 256;      // u = k8*64 + b
            const int k8 = u >> 6, b = u & 63;
            unsigned short oh[8], ol[8];
#pragma unroll
            for (int e = 0; e < 8; ++e) {
                unsigned hi, lo;
                split_bf16(tile[b][k8 * 8 + e], hi, lo);
                oh[e] = (unsigned short)hi;
                ol[e] = (unsigned short)lo;
            }
            const size_t idx = (size_t)t * XT_STRIDE + ((kc >> 3) + k8) * 512 + b * 8;
            *(uint4*)(xH + idx) = *(const uint4*)oh;   // lanes adjacent: coalesced
            *(uint4*)(xL + idx) = *(const uint4*)ol;
        }
        __syncthreads();
    }
}

__global__ void __launch_bounds__(NTHR, 2)   // 2 waves/EU -> <=256 VGPR, 1 block/CU
lstm_mfma(const unsigned short* __restrict__ xH,
          const unsigned short* __restrict__ xL,
          const int*   __restrict__ lens,
          const float* __restrict__ Wih,     // [4H][I]
          const float* __restrict__ Whh,     // [4H][H]
          const float* __restrict__ bih,
          const float* __restrict__ bhh,
          unsigned short* __restrict__ hH,   // [2][H/8][B][8]
          unsigned short* __restrict__ hL,
          int*   __restrict__ syncp,
          float* __restrict__ out)           // [B][H]
{
    __shared__ float red[2][2][2][16][20];   // [mt][slot][nt][bsub][r16 pad20] = 10 KB

    const int tid  = (int)threadIdx.x;
    const int l    = tid & 63;
    const int p    = __builtin_amdgcn_readfirstlane(tid >> 6);  // wave 0..7
    const int kh   = p & 3;                  // k-split 0..3
    const int mt   = p >> 2;                 // m-tile 0..1
    const int bsub = l & 15;
    const int q    = l >> 4;                 // quad

    const int jt = (int)blockIdx.x >> 1;
    const int bh = (int)blockIdx.x & 1;
    const int j0 = jt * 8;

    const int bofs[2] = {(bh * 32 + bsub) * 8, (bh * 32 + 16 + bsub) * 8};

    // ---- weight A-fragments -> registers (persist across all t) ----
    // A-frag: m = lane&15, k = quad*8+e.  row(m) = (m&3)*HH + j0 + mt*4 + (m>>2)
    const int row = (l & 3) * HH + j0 + mt * 4 + ((l & 15) >> 2);
    bf16x8 whi[12], wlo[12];
#pragma unroll
    for (int kt = 0; kt < 12; ++kt) {
        const int ktg = (kt < 4) ? (4 * kh + kt) : (16 + 8 * kh + (kt - 4));
        const float* src = (ktg < 16)
            ? (Wih + (size_t)row * II + ktg * 32 + q * 8)
            : (Whh + (size_t)row * HH + (ktg - 16) * 32 + q * 8);
        const float4 w0 = *(const float4*)src;
        const float4 w1 = *(const float4*)(src + 4);
        const float wf[8] = {w0.x, w0.y, w0.z, w0.w, w1.x, w1.y, w1.z, w1.w};
#pragma unroll
        for (int e = 0; e < 8; ++e) {
            unsigned hi, lo;
            split_bf16(wf[e], hi, lo);
            whi[kt][e] = (short)hi;
            wlo[kt][e] = (short)lo;
        }
    }

    // ---- per-cell state (kh==0 waves: gate math, 2 cells/thread) ----
    float bias[4], c[2] = {0.f, 0.f}, lasth[2] = {0.f, 0.f};
    int len[2] = {0, 0};
    const int jcell = j0 + mt * 4 + q;
    const int jlow  = mt * 4 + q;
    const size_t hblk = (size_t)(j0 >> 3) * 512;     // block's region in h planes
    if (kh == 0) {
#pragma unroll
        for (int g = 0; g < 4; ++g)
            bias[g] = bih[g * HH + jcell] + bhh[g * HH + jcell];
#pragma unroll
        for (int nt = 0; nt < 2; ++nt) {
            const int b = bh * 32 + nt * 16 + bsub;
            len[nt] = lens[b];
            store_wt_u16(hH + hblk + b * 8 + jlow, 0);   // h_0 = 0, buffer 0
            store_wt_u16(hL + hblk + b * 8 + jlow, 0);
        }
    }

    int bar = 1;
    __syncthreads();                          // drain init stores (vmcnt 0)
    if (tid == 0) atomic_add_rlx(syncp);

    // ---- x-part for t=0 into 3 independent streams (overlaps barrier) ----
    f32x4 s0[2], s1[2], s2[2];
#pragma unroll
    for (int nt = 0; nt < 2; ++nt)
        s0[nt] = s1[nt] = s2[nt] = (f32x4){0.f, 0.f, 0.f, 0.f};
    {
        const unsigned short* xh = xH;        // t = 0
        const unsigned short* xl = xL;
#pragma unroll
        for (int xi = 0; xi < 4; ++xi) {
            const int idx = ((4 * kh + xi) * 4 + q) * 512;
#pragma unroll
            for (int nt = 0; nt < 2; ++nt) {
                const bf16x8 ahi = *(const bf16x8*)(xh + idx + bofs[nt]);
                const bf16x8 alo = *(const bf16x8*)(xl + idx + bofs[nt]);
                s0[nt] = MFMA(whi[xi], ahi, s0[nt]);
                s1[nt] = MFMA(whi[xi], alo, s1[nt]);
                s2[nt] = MFMA(wlo[xi], ahi, s2[nt]);
            }
        }
    }

    if (tid == 0) while (load_rlx(syncp) < NBLK * bar) __builtin_amdgcn_s_sleep(1);
    __syncthreads();
    __builtin_amdgcn_fence(__ATOMIC_ACQUIRE, "agent");   // invalidate stale caches

    for (int t = 0; t < TT; ++t) {
        // ---- h-part: k = 256*kh + [0,256) ----
        const unsigned short* hph = hH + (t & 1) * HBUF_STRIDE;
        const unsigned short* hpl = hL + (t & 1) * HBUF_STRIDE;
#pragma unroll
        for (int hi2 = 0; hi2 < 8; ++hi2) {
            const int idx = (kh * 32 + hi2 * 4 + q) * 512;
#pragma unroll
            for (int nt = 0; nt < 2; ++nt) {
                const bf16x8 ahi = *(const bf16x8*)(hph + idx + bofs[nt]);
                const bf16x8 alo = *(const bf16x8*)(hpl + idx + bofs[nt]);
                s0[nt] = MFMA(whi[4 + hi2], ahi, s0[nt]);
                s1[nt] = MFMA(whi[4 + hi2], alo, s1[nt]);
                s2[nt] = MFMA(wlo[4 + hi2], ahi, s2[nt]);
            }
        }

        // ---- merge streams, cross-wave reduction kh{2,3}->{0,1}, 1->0 ----
        f32x4 acc[2];
#pragma unroll
        for (int nt = 0; nt < 2; ++nt) acc[nt] = s0[nt] + s1[nt] + s2[nt];

        if (kh >= 2) {
#pragma unroll
            for (int nt = 0; nt < 2; ++nt)
                *(f32x4*)&red[mt][kh - 2][nt][bsub][4 * q] = acc[nt];
        }
        __syncthreads();
        if (kh < 2) {
#pragma unroll
            for (int nt = 0; nt < 2; ++nt)
                acc[nt] += *(f32x4*)&red[mt][kh][nt][bsub][4 * q];
        }
        __syncthreads();
        if (kh == 1) {
#pragma unroll
            for (int nt = 0; nt < 2; ++nt)
                *(f32x4*)&red[mt][0][nt][bsub][4 * q] = acc[nt];
        }
        __syncthreads();

        // ---- gate math (kh==0; D: reg=gate, quad=jj) + h store ----
        if (kh == 0) {
            unsigned short* dsth = hH + ((t + 1) & 1) * HBUF_STRIDE + hblk;
            unsigned short* dstl = hL + ((t + 1) & 1) * HBUF_STRIDE + hblk;
#pragma unroll
            for (int nt = 0; nt < 2; ++nt) {
                const f32x4 r4 = *(f32x4*)&red[mt][0][nt][bsub][4 * q];
                const float ig = fast_sigmoid(acc[nt][0] + r4[0] + bias[0]);
                const float fg = fast_sigmoid(acc[nt][1] + r4[1] + bias[1]);
                const float gg = fast_tanh   (acc[nt][2] + r4[2] + bias[2]);
                const float og = fast_sigmoid(acc[nt][3] + r4[3] + bias[3]);
                c[nt] = fg * c[nt] + ig * gg;
                const float h = og * fast_tanh(c[nt]);
                unsigned hi, lo;
                split_bf16(h, hi, lo);
                const int b = bh * 32 + nt * 16 + bsub;
                store_wt_u16(dsth + b * 8 + jlow, (unsigned short)hi);
                store_wt_u16(dstl + b * 8 + jlow, (unsigned short)lo);
                if (t == len[nt] - 1) lasth[nt] = h;
            }
        }

        // ---- flat barrier, overlapped with x-part for t+1 ----
        ++bar;
        __syncthreads();                      // drain h stores before arrive
        if (tid == 0) atomic_add_rlx(syncp);

#pragma unroll
        for (int nt = 0; nt < 2; ++nt)
            s0[nt] = s1[nt] = s2[nt] = (f32x4){0.f, 0.f, 0.f, 0.f};
        if (t + 1 < TT) {
            const unsigned short* xh = xH + (size_t)(t + 1) * XT_STRIDE;
            const unsigned short* xl = xL + (size_t)(t + 1) * XT_STRIDE;
#pragma unroll
            for (int xi = 0; xi < 4; ++xi) {
                const int idx = ((4 * kh + xi) * 4 + q) * 512;
#pragma unroll
                for (int nt = 0; nt < 2; ++nt) {
                    const bf16x8 ahi = *(const bf16x8*)(xh + idx + bofs[nt]);
                    const bf16x8 alo = *(const bf16x8*)(xl + idx + bofs[nt]);
                    s0[nt] = MFMA(whi[xi], ahi, s0[nt]);
                    s1[nt] = MFMA(whi[xi], alo, s1[nt]);
                    s2[nt] = MFMA(wlo[xi], ahi, s2[nt]);
                }
            }
        }

        if (tid == 0) while (load_rlx(syncp) < NBLK * bar) __builtin_amdgcn_s_sleep(1);
        __syncthreads();
        __builtin_amdgcn_fence(__ATOMIC_ACQUIRE, "agent");
    }

    // ---- epilogue ----
    if (kh == 0) {
#pragma unroll
        for (int nt = 0; nt < 2; ++nt) {
            const int b = bh * 32 + nt * 16 + bsub;
            out[(size_t)b * HH + jcell] = lasth[nt];
        }
    }
}

extern "C" void kernel_launch(void* const* d_in, const int* in_sizes, int n_in,
                              void* d_out, int out_size, void* d_ws, size_t ws_size,
                              hipStream_t stream)
{
    const float* seq  = (const float*)d_in[0];
    const int*   lens = (const int*)  d_in[1];
    const float* Wih  = (const float*)d_in[2];
    const float* Whh  = (const float*)d_in[3];
    const float* bih  = (const float*)d_in[4];
    const float* bhh  = (const float*)d_in[5];
    float* out = (float*)d_out;

    char* ws = (char*)d_ws;
    int*            syncp = (int*)           (ws + WS_SYNC_OFF);
    unsigned short* hH    = (unsigned short*)(ws + WS_HPAKH_OFF);
    unsigned short* hL    = (unsigned short*)(ws + WS_HPAKL_OFF);
    unsigned short* xH    = (unsigned short*)(ws + WS_XPAKH_OFF);
    unsigned short* xL    = (unsigned short*)(ws + WS_XPAKL_OFF);

    hipMemsetAsync(syncp, 0, 8192, stream);
    transpose_pack_x<<<dim3(TT), dim3(256), 0, stream>>>(seq, xH, xL);
    lstm_mfma<<<dim3(NBLK), dim3(NTHR), 0, stream>>>(xH, xL, lens, Wih, Whh, bih, bhh,
                                                     hH, hL, syncp, out);
}

// Round 6
// 8524.787 us; speedup vs baseline: 15.2159x; 1.3157x over previous
//
#include <hip/hip_runtime.h>

// LSTM B=64 T=512 I=512 H=1024 — round 6: barrier-free flag pipeline.
// Round-5 diagnosis: ~20us/step structural sync tax (single-line 256-way RMW
// barrier + per-step agent-acquire fence = full L1/L2 invalidate + IF refill).
// Fix: no barrier, no fences in the loop.
//  - Producers publish h-chunks via monotonic per-chunk flags (single writer,
//    plain atomic store after s_waitcnt vmcnt(0) on write-through h stores).
//  - Consumers poll their 64 needed flags with one 64-lane coherent load +
//    __all, then read h with agent-scope relaxed atomic dword loads (bypass
//    stale L1/L2) -> x/weights stay cached forever, nothing invalidated.
//  - Skew bound (D=2): seeing all flags>=t+1 implies every peer finished
//    reading h_{t-1} (data dependency), so overwriting h_{t-1} with h_{t+1}
//    is safe with 2 buffers. LDS `red` parity-indexed (red[t&1]) — the shared
//    syncthreads of step t+1 order step-t readers before step-t+2 writers.

typedef short bf16x8 __attribute__((ext_vector_type(8)));
typedef float f32x4  __attribute__((ext_vector_type(4)));

#define BB 64
#define TT 512
#define II 512
#define HH 1024

#define NBLK 256
#define NTHR 512

// ws layout (bytes)
#define WS_FLAG_OFF  0                       // 512 ints flags (memset 8K / call)
#define WS_HPAKH_OFF 8192                    // u16 [2][HH/8][BB][8] = 256 KB
#define WS_HPAKL_OFF (8192 + 262144)
#define WS_XPAKH_OFF (1 << 20)               // u16 [TT][II/8][BB][8] = 32 MB
#define WS_XPAKL_OFF ((1 << 20) + (32u << 20))

#define HBUF_STRIDE 65536                    // u16 per h buffer
#define XT_STRIDE   32768                    // u16 per timestep of x

__device__ __forceinline__ void store_wt_u16(unsigned short* p, unsigned short v) {
    __hip_atomic_store(p, v, __ATOMIC_RELAXED, __HIP_MEMORY_SCOPE_AGENT);
}
__device__ __forceinline__ void store_flag(int* p, int v) {
    __hip_atomic_store(p, v, __ATOMIC_RELAXED, __HIP_MEMORY_SCOPE_AGENT);
}
__device__ __forceinline__ int load_flag(const int* p) {
    return __hip_atomic_load(p, __ATOMIC_RELAXED, __HIP_MEMORY_SCOPE_AGENT);
}
// coherent 16B fragment load as 4 agent-scope dwords (bypass stale L1/L2)
__device__ __forceinline__ bf16x8 load_frag_coh(const unsigned short* p) {
    const unsigned* u = (const unsigned*)p;
    union { unsigned w[4]; bf16x8 v; } cv;
#pragma unroll
    for (int i = 0; i < 4; ++i)
        cv.w[i] = __hip_atomic_load(u + i, __ATOMIC_RELAXED, __HIP_MEMORY_SCOPE_AGENT);
    return cv.v;
}

__device__ __forceinline__ float fast_sigmoid(float x) {
    return 1.0f / (1.0f + __expf(-x));
}
__device__ __forceinline__ float fast_tanh(float x) {
    x = fminf(15.0f, fmaxf(-15.0f, x));
    const float e = __expf(2.0f * x);
    return (e - 1.0f) / (e + 1.0f);
}

// fp32 -> bf16 hi + bf16 lo-of-residual (RNE both)
__device__ __forceinline__ void split_bf16(float x, unsigned& hi, unsigned& lo)
{
    unsigned b = __float_as_uint(x);
    hi = (b + 0x7fffu + ((b >> 16) & 1u)) >> 16;
    float r = x - __uint_as_float(hi << 16);
    unsigned bl = __float_as_uint(r);
    lo = (bl + 0x7fffu + ((bl >> 16) & 1u)) >> 16;
}

#define MFMA(A, B, C) __builtin_amdgcn_mfma_f32_16x16x32_bf16((A), (B), (C), 0, 0, 0)

// x -> split planes, layout [t][k>>3][b][k&7] u16 per plane
__global__ void __launch_bounds__(256)
transpose_pack_x(const float* __restrict__ x,
                 unsigned short* __restrict__ xH, unsigned short* __restrict__ xL)
{
    __shared__ float tile[64][65];
    const int t   = (int)blockIdx.x;
    const int tid = (int)threadIdx.x;
    const int li  = tid & 63;
    const int w4  = tid >> 6;

    for (int kc = 0; kc < II; kc += 64) {
#pragma unroll
        for (int r = 0; r < 16; ++r) {
            const int b = w4 * 16 + r;
            tile[b][li] = x[((size_t)b * TT + t) * II + kc + li];
        }
        __syncthreads();
#pragma unroll
        for (int half = 0; half < 2; ++half) {
            const int u  = tid + half * 256;      // u = k8*64 + b
            const int k8 = u >> 6, b = u & 63;
            unsigned short oh[8], ol[8];
#pragma unroll
            for (int e = 0; e < 8; ++e) {
                unsigned hi, lo;
                split_bf16(tile[b][k8 * 8 + e], hi, lo);
                oh[e] = (unsigned short)hi;
                ol[e] = (unsigned short)lo;
            }
            const size_t idx = (size_t)t * XT_STRIDE + ((kc >> 3) + k8) * 512 + b * 8;
            *(uint4*)(xH + idx) = *(const uint4*)oh;
            *(uint4*)(xL + idx) = *(const uint4*)ol;
        }
        __syncthreads();
    }
}

__global__ void __launch_bounds__(NTHR, 2)   // <=256 VGPR, 1 block/CU
lstm_mfma(const unsigned short* __restrict__ xH,
          const unsigned short* __restrict__ xL,
          const int*   __restrict__ lens,
          const float* __restrict__ Wih,     // [4H][I]
          const float* __restrict__ Whh,     // [4H][H]
          const float* __restrict__ bih,
          const float* __restrict__ bhh,
          unsigned short* __restrict__ hH,   // [2][H/8][B][8]
          unsigned short* __restrict__ hL,
          int*   __restrict__ flags,         // [2 halves][256 chunks]
          float* __restrict__ out)           // [B][H]
{
    __shared__ float red[2][2][2][2][16][20];  // [parity][mt][slot][nt][bsub][pad20] = 20 KB

    const int tid  = (int)threadIdx.x;
    const int l    = tid & 63;
    const int p    = __builtin_amdgcn_readfirstlane(tid >> 6);  // wave 0..7
    const int kh   = p & 3;                  // k-split 0..3
    const int mt   = p >> 2;                 // m-tile 0..1
    const int bsub = l & 15;
    const int q    = l >> 4;                 // quad

    const int jt = (int)blockIdx.x >> 1;
    const int bh = (int)blockIdx.x & 1;
    const int j0 = jt * 8;

    const int bofs[2] = {(bh * 32 + bsub) * 8, (bh * 32 + 16 + bsub) * 8};

    // ---- weight A-fragments -> registers (persist across all t) ----
    const int row = (l & 3) * HH + j0 + mt * 4 + ((l & 15) >> 2);
    bf16x8 whi[12], wlo[12];
#pragma unroll
    for (int kt = 0; kt < 12; ++kt) {
        const int ktg = (kt < 4) ? (4 * kh + kt) : (16 + 8 * kh + (kt - 4));
        const float* src = (ktg < 16)
            ? (Wih + (size_t)row * II + ktg * 32 + q * 8)
            : (Whh + (size_t)row * HH + (ktg - 16) * 32 + q * 8);
        const float4 w0 = *(const float4*)src;
        const float4 w1 = *(const float4*)(src + 4);
        const float wf[8] = {w0.x, w0.y, w0.z, w0.w, w1.x, w1.y, w1.z, w1.w};
#pragma unroll
        for (int e = 0; e < 8; ++e) {
            unsigned hi, lo;
            split_bf16(wf[e], hi, lo);
            whi[kt][e] = (short)hi;
            wlo[kt][e] = (short)lo;
        }
    }

    // ---- per-cell state; init h_0 and publish flag=1 ----
    float bias[4], c[2] = {0.f, 0.f}, lasth[2] = {0.f, 0.f};
    int len[2] = {0, 0};
    const int jcell = j0 + mt * 4 + q;
    const int jlow  = mt * 4 + q;
    const size_t hblk = (size_t)jt * 512;
    int* myflag = flags + bh * 256 + jt * 2 + mt;

    if (kh == 0) {
#pragma unroll
        for (int g = 0; g < 4; ++g)
            bias[g] = bih[g * HH + jcell] + bhh[g * HH + jcell];
#pragma unroll
        for (int nt = 0; nt < 2; ++nt) {
            const int b = bh * 32 + nt * 16 + bsub;
            len[nt] = lens[b];
            store_wt_u16(hH + hblk + b * 8 + jlow, 0);   // h_0 = 0, buffer 0
            store_wt_u16(hL + hblk + b * 8 + jlow, 0);
        }
        asm volatile("s_waitcnt vmcnt(0)" ::: "memory");  // stores globally visible
        if (l == 0) store_flag(myflag, 1);                // h_0 ready
    }

    const int* pollp = flags + bh * 256 + 64 * kh + l;    // this wave's 64 flags

    for (int t = 0; t < TT; ++t) {
        // ---- x-part (plain cached loads; L2 never invalidated) ----
        f32x4 s0[2], s1[2], s2[2];
#pragma unroll
        for (int nt = 0; nt < 2; ++nt)
            s0[nt] = s1[nt] = s2[nt] = (f32x4){0.f, 0.f, 0.f, 0.f};
        {
            const unsigned short* xh = xH + (size_t)t * XT_STRIDE;
            const unsigned short* xl = xL + (size_t)t * XT_STRIDE;
#pragma unroll
            for (int xi = 0; xi < 4; ++xi) {
                const int idx = ((4 * kh + xi) * 4 + q) * 512;
#pragma unroll
                for (int nt = 0; nt < 2; ++nt) {
                    const bf16x8 ahi = *(const bf16x8*)(xh + idx + bofs[nt]);
                    const bf16x8 alo = *(const bf16x8*)(xl + idx + bofs[nt]);
                    s0[nt] = MFMA(whi[xi], ahi, s0[nt]);
                    s1[nt] = MFMA(whi[xi], alo, s1[nt]);
                    s2[nt] = MFMA(wlo[xi], ahi, s2[nt]);
                }
            }
        }

        // ---- wait for the 64 h_t chunks this wave consumes ----
        {
            const int need = t + 1;
            while (true) {
                const int v = load_flag(pollp);
                if (__all(v >= need)) break;
                __builtin_amdgcn_s_sleep(1);
            }
            asm volatile("" ::: "memory");   // loads below stay below the poll
        }

        // ---- h-part: coherent fragment loads + MFMA ----
        const unsigned short* hph = hH + (t & 1) * HBUF_STRIDE;
        const unsigned short* hpl = hL + (t & 1) * HBUF_STRIDE;
#pragma unroll
        for (int hi2 = 0; hi2 < 8; ++hi2) {
            const int idx = (kh * 32 + hi2 * 4 + q) * 512;
#pragma unroll
            for (int nt = 0; nt < 2; ++nt) {
                const bf16x8 ahi = load_frag_coh(hph + idx + bofs[nt]);
                const bf16x8 alo = load_frag_coh(hpl + idx + bofs[nt]);
                s0[nt] = MFMA(whi[4 + hi2], ahi, s0[nt]);
                s1[nt] = MFMA(whi[4 + hi2], alo, s1[nt]);
                s2[nt] = MFMA(wlo[4 + hi2], ahi, s2[nt]);
            }
        }

        // ---- merge streams + cross-wave reduction (parity LDS) ----
        f32x4 acc[2];
#pragma unroll
        for (int nt = 0; nt < 2; ++nt) acc[nt] = s0[nt] + s1[nt] + s2[nt];
        const int pa = t & 1;

        if (kh >= 2) {
#pragma unroll
            for (int nt = 0; nt < 2; ++nt)
                *(f32x4*)&red[pa][mt][kh - 2][nt][bsub][4 * q] = acc[nt];
        }
        __syncthreads();
        if (kh < 2) {
#pragma unroll
            for (int nt = 0; nt < 2; ++nt)
                acc[nt] += *(f32x4*)&red[pa][mt][kh][nt][bsub][4 * q];
        }
        __syncthreads();
        if (kh == 1) {
#pragma unroll
            for (int nt = 0; nt < 2; ++nt)
                *(f32x4*)&red[pa][mt][0][nt][bsub][4 * q] = acc[nt];
        }
        __syncthreads();

        // ---- gate math (kh==0), h_{t+1} store, flag publish ----
        if (kh == 0) {
            unsigned short* dsth = hH + ((t + 1) & 1) * HBUF_STRIDE + hblk;
            unsigned short* dstl = hL + ((t + 1) & 1) * HBUF_STRIDE + hblk;
#pragma unroll
            for (int nt = 0; nt < 2; ++nt) {
                const f32x4 r4 = *(f32x4*)&red[pa][mt][0][nt][bsub][4 * q];
                const float ig = fast_sigmoid(acc[nt][0] + r4[0] + bias[0]);
                const float fg = fast_sigmoid(acc[nt][1] + r4[1] + bias[1]);
                const float gg = fast_tanh   (acc[nt][2] + r4[2] + bias[2]);
                const float og = fast_sigmoid(acc[nt][3] + r4[3] + bias[3]);
                c[nt] = fg * c[nt] + ig * gg;
                const float h = og * fast_tanh(c[nt]);
                unsigned hi, lo;
                split_bf16(h, hi, lo);
                const int b = bh * 32 + nt * 16 + bsub;
                store_wt_u16(dsth + b * 8 + jlow, (unsigned short)hi);
                store_wt_u16(dstl + b * 8 + jlow, (unsigned short)lo);
                if (t == len[nt] - 1) lasth[nt] = h;
            }
            asm volatile("s_waitcnt vmcnt(0)" ::: "memory");  // h stores visible
            if (l == 0) store_flag(myflag, t + 2);            // h_{t+1} ready
        }
    }

    // ---- epilogue ----
    if (kh == 0) {
#pragma unroll
        for (int nt = 0; nt < 2; ++nt) {
            const int b = bh * 32 + nt * 16 + bsub;
            out[(size_t)b * HH + jcell] = lasth[nt];
        }
    }
}

extern "C" void kernel_launch(void* const* d_in, const int* in_sizes, int n_in,
                              void* d_out, int out_size, void* d_ws, size_t ws_size,
                              hipStream_t stream)
{
    const float* seq  = (const float*)d_in[0];
    const int*   lens = (const int*)  d_in[1];
    const float* Wih  = (const float*)d_in[2];
    const float* Whh  = (const float*)d_in[3];
    const float* bih  = (const float*)d_in[4];
    const float* bhh  = (const float*)d_in[5];
    float* out = (float*)d_out;

    char* ws = (char*)d_ws;
    int*            flags = (int*)           (ws + WS_FLAG_OFF);
    unsigned short* hH    = (unsigned short*)(ws + WS_HPAKH_OFF);
    unsigned short* hL    = (unsigned short*)(ws + WS_HPAKL_OFF);
    unsigned short* xH    = (unsigned short*)(ws + WS_XPAKH_OFF);
    unsigned short* xL    = (unsigned short*)(ws + WS_XPAKL_OFF);

    hipMemsetAsync(flags, 0, 8192, stream);   // monotonic flags start at 0
    transpose_pack_x<<<dim3(TT), dim3(256), 0, stream>>>(seq, xH, xL);
    lstm_mfma<<<dim3(NBLK), dim3(NTHR), 0, stream>>>(xH, xL, lens, Wih, Whh, bih, bhh,
                                                     hH, hL, flags, out);
}

// Round 7
// 3273.662 us; speedup vs baseline: 39.6229x; 2.6041x over previous
//
#include <hip/hip_runtime.h>

// LSTM B=64 T=512 I=512 H=1024 — round 7.
// Round-6 diagnosis: coherent h loads split into 4B dword atomics (4x IF
// transaction amplification, ~128 RTTs/wave/step) + 2048 waves gather-polling
// 8 flag lines through IF + LDS red conflicts. Fixes:
//  - h frags: inline-asm global_load_dwordx4 sc0 sc1, 16 issued per batch,
//    ONE s_waitcnt vmcnt(0) (values flow through the wait-asm as +v operands
//    so MFMAs cannot be scheduled before the wait). 2 batches/step/wave.
//  - sync: 8 quarter counters (256B apart). Producer kh0-waves fetch_add once
//    after store-ack; consumers poll ONE broadcast dword until 64*(t+1).
//  - red: single-phase (kh>=1 write, 1 syncthreads, kh0 sums), parity-indexed,
//    pad-17 scalar floats (<=2-way bank aliasing = free).
// Skew safety (D=2): producer at step t passed poll>=64*(t+1) => all blocks
// published h_t => all waves consumed h_{t-1} (publish is data-dependent on
// every wave's h-loads via red+syncthreads) => overwriting h_{t-1} is safe.

typedef short bf16x8 __attribute__((ext_vector_type(8)));
typedef float f32x4  __attribute__((ext_vector_type(4)));
typedef unsigned u32x4 __attribute__((ext_vector_type(4)));

#define BB 64
#define TT 512
#define II 512
#define HH 1024

#define NBLK 256
#define NTHR 512

// ws layout (bytes)
#define WS_CNT_OFF   0                       // 8 counters, 256B apart (memset 8K)
#define WS_HPAKH_OFF 8192                    // u16 [2][HH/8][BB][8] = 256 KB
#define WS_HPAKL_OFF (8192 + 262144)
#define WS_XPAKH_OFF (1 << 20)               // u16 [TT][II/8][BB][8] = 32 MB
#define WS_XPAKL_OFF ((1 << 20) + (32u << 20))

#define HBUF_STRIDE 65536                    // u16 per h buffer
#define XT_STRIDE   32768                    // u16 per timestep of x

__device__ __forceinline__ int atomic_add_rlx(int* p) {
    return __hip_atomic_fetch_add(p, 1, __ATOMIC_RELAXED, __HIP_MEMORY_SCOPE_AGENT);
}
__device__ __forceinline__ int load_rlx(const int* p) {
    return __hip_atomic_load(p, __ATOMIC_RELAXED, __HIP_MEMORY_SCOPE_AGENT);
}
__device__ __forceinline__ void store_wt_u16(unsigned short* p, unsigned short v) {
    __hip_atomic_store(p, v, __ATOMIC_RELAXED, __HIP_MEMORY_SCOPE_AGENT);
}

__device__ __forceinline__ float fast_sigmoid(float x) {
    return 1.0f / (1.0f + __expf(-x));
}
__device__ __forceinline__ float fast_tanh(float x) {
    x = fminf(15.0f, fmaxf(-15.0f, x));
    const float e = __expf(2.0f * x);
    return (e - 1.0f) / (e + 1.0f);
}

// fp32 -> bf16 hi + bf16 lo-of-residual (RNE both)
__device__ __forceinline__ void split_bf16(float x, unsigned& hi, unsigned& lo)
{
    unsigned b = __float_as_uint(x);
    hi = (b + 0x7fffu + ((b >> 16) & 1u)) >> 16;
    float r = x - __uint_as_float(hi << 16);
    unsigned bl = __float_as_uint(r);
    lo = (bl + 0x7fffu + ((bl >> 16) & 1u)) >> 16;
}

#define MFMA(A, B, C) __builtin_amdgcn_mfma_f32_16x16x32_bf16((A), (B), (C), 0, 0, 0)

// coherent 16B load, issued WITHOUT wait (pair with WAIT16 below)
__device__ __forceinline__ void issue_coh(const unsigned short* p, u32x4& d)
{
    asm volatile("global_load_dwordx4 %0, %1, off sc0 sc1" : "=v"(d) : "v"(p));
}
// drain all VMEM; loaded values flow THROUGH this asm so uses can't be hoisted
#define WAIT16(A, B)                                                          \
    asm volatile("s_waitcnt vmcnt(0)"                                         \
        : "+v"(A[0]), "+v"(A[1]), "+v"(A[2]), "+v"(A[3]),                     \
          "+v"(A[4]), "+v"(A[5]), "+v"(A[6]), "+v"(A[7]),                     \
          "+v"(B[0]), "+v"(B[1]), "+v"(B[2]), "+v"(B[3]),                     \
          "+v"(B[4]), "+v"(B[5]), "+v"(B[6]), "+v"(B[7]) :: "memory")

// x -> split planes, layout [t][k>>3][b][k&7] u16 per plane
__global__ void __launch_bounds__(256)
transpose_pack_x(const float* __restrict__ x,
                 unsigned short* __restrict__ xH, unsigned short* __restrict__ xL)
{
    __shared__ float tile[64][65];
    const int t   = (int)blockIdx.x;
    const int tid = (int)threadIdx.x;
    const int li  = tid & 63;
    const int w4  = tid >> 6;

    for (int kc = 0; kc < II; kc += 64) {
#pragma unroll
        for (int r = 0; r < 16; ++r) {
            const int b = w4 * 16 + r;
            tile[b][li] = x[((size_t)b * TT + t) * II + kc + li];
        }
        __syncthreads();
#pragma unroll
        for (int half = 0; half < 2; ++half) {
            const int u  = tid + half * 256;      // u = k8*64 + b
            const int k8 = u >> 6, b = u & 63;
            unsigned short oh[8], ol[8];
#pragma unroll
            for (int e = 0; e < 8; ++e) {
                unsigned hi, lo;
                split_bf16(tile[b][k8 * 8 + e], hi, lo);
                oh[e] = (unsigned short)hi;
                ol[e] = (unsigned short)lo;
            }
            const size_t idx = (size_t)t * XT_STRIDE + ((kc >> 3) + k8) * 512 + b * 8;
            *(uint4*)(xH + idx) = *(const uint4*)oh;
            *(uint4*)(xL + idx) = *(const uint4*)ol;
        }
        __syncthreads();
    }
}

__global__ void __launch_bounds__(NTHR, 2)   // <=256 VGPR, 1 block/CU
lstm_mfma(const unsigned short* __restrict__ xH,
          const unsigned short* __restrict__ xL,
          const int*   __restrict__ lens,
          const float* __restrict__ Wih,     // [4H][I]
          const float* __restrict__ Whh,     // [4H][H]
          const float* __restrict__ bih,
          const float* __restrict__ bhh,
          unsigned short* __restrict__ hH,   // [2][H/8][B][8]
          unsigned short* __restrict__ hL,
          int*   __restrict__ cnts,          // 8 counters, 64-int stride
          float* __restrict__ out)           // [B][H]
{
    __shared__ float red[2][2][3][2][16][17];  // [parity][mt][src-1][nt][bsub][pad17] ~26KB

    const int tid  = (int)threadIdx.x;
    const int l    = tid & 63;
    const int p    = __builtin_amdgcn_readfirstlane(tid >> 6);  // wave 0..7
    const int kh   = p & 3;                  // k-split 0..3
    const int mt   = p >> 2;                 // m-tile 0..1
    const int bsub = l & 15;
    const int q    = l >> 4;                 // quad

    const int jt = (int)blockIdx.x >> 1;
    const int bh = (int)blockIdx.x & 1;
    const int j0 = jt * 8;

    const int bofs[2] = {(bh * 32 + bsub) * 8, (bh * 32 + 16 + bsub) * 8};

    int*       prodc = cnts + (bh * 4 + (jt >> 5)) * 64;   // my quarter's counter
    const int* consc = cnts + (bh * 4 + kh) * 64;          // quarter I consume

    // ---- weight A-fragments -> registers (persist across all t) ----
    const int row = (l & 3) * HH + j0 + mt * 4 + ((l & 15) >> 2);
    bf16x8 whi[12], wlo[12];
#pragma unroll
    for (int kt = 0; kt < 12; ++kt) {
        const int ktg = (kt < 4) ? (4 * kh + kt) : (16 + 8 * kh + (kt - 4));
        const float* src = (ktg < 16)
            ? (Wih + (size_t)row * II + ktg * 32 + q * 8)
            : (Whh + (size_t)row * HH + (ktg - 16) * 32 + q * 8);
        const float4 w0 = *(const float4*)src;
        const float4 w1 = *(const float4*)(src + 4);
        const float wf[8] = {w0.x, w0.y, w0.z, w0.w, w1.x, w1.y, w1.z, w1.w};
#pragma unroll
        for (int e = 0; e < 8; ++e) {
            unsigned hi, lo;
            split_bf16(wf[e], hi, lo);
            whi[kt][e] = (short)hi;
            wlo[kt][e] = (short)lo;
        }
    }

    // ---- per-cell state; init h_0, ack, publish ----
    float bias[4], c[2] = {0.f, 0.f}, lasth[2] = {0.f, 0.f};
    int len[2] = {0, 0};
    const int jcell = j0 + mt * 4 + q;
    const int jlow  = mt * 4 + q;
    const size_t hblk = (size_t)jt * 512;

    if (kh == 0) {
#pragma unroll
        for (int g = 0; g < 4; ++g)
            bias[g] = bih[g * HH + jcell] + bhh[g * HH + jcell];
#pragma unroll
        for (int nt = 0; nt < 2; ++nt) {
            const int b = bh * 32 + nt * 16 + bsub;
            len[nt] = lens[b];
            store_wt_u16(hH + hblk + b * 8 + jlow, 0);   // h_0 = 0, buffer 0
            store_wt_u16(hL + hblk + b * 8 + jlow, 0);
        }
        asm volatile("s_waitcnt vmcnt(0)" ::: "memory");
        if (l == 0) atomic_add_rlx(prodc);               // -> 64 when all ready
    }

    for (int t = 0; t < TT; ++t) {
        // ---- x-part (plain cached b128 loads; independent of h_t) ----
        f32x4 s0[2], s1[2], s2[2];
#pragma unroll
        for (int nt = 0; nt < 2; ++nt)
            s0[nt] = s1[nt] = s2[nt] = (f32x4){0.f, 0.f, 0.f, 0.f};
        {
            const unsigned short* xh = xH + (size_t)t * XT_STRIDE;
            const unsigned short* xl = xL + (size_t)t * XT_STRIDE;
#pragma unroll
            for (int xi = 0; xi < 4; ++xi) {
                const int idx = ((4 * kh + xi) * 4 + q) * 512;
#pragma unroll
                for (int nt = 0; nt < 2; ++nt) {
                    const bf16x8 ahi = *(const bf16x8*)(xh + idx + bofs[nt]);
                    const bf16x8 alo = *(const bf16x8*)(xl + idx + bofs[nt]);
                    s0[nt] = MFMA(whi[xi], ahi, s0[nt]);
                    s1[nt] = MFMA(whi[xi], alo, s1[nt]);
                    s2[nt] = MFMA(wlo[xi], ahi, s2[nt]);
                }
            }
        }

        // ---- wait: my k-quarter of h_t fully published (single dword poll) ----
        {
            const int need = 64 * (t + 1);
            while (load_rlx(consc) < need)
                __builtin_amdgcn_s_sleep(1);
            asm volatile("" ::: "memory");
        }

        // ---- h-part: 2 batches of 16 coherent b128 loads, 1 wait each ----
        const unsigned short* hph = hH + (t & 1) * HBUF_STRIDE;
        const unsigned short* hpl = hL + (t & 1) * HBUF_STRIDE;
#pragma unroll
        for (int nt = 0; nt < 2; ++nt) {
            u32x4 fh[8], fl[8];
#pragma unroll
            for (int hi2 = 0; hi2 < 8; ++hi2) {
                const int idx = (kh * 32 + hi2 * 4 + q) * 512 + bofs[nt];
                issue_coh(hph + idx, fh[hi2]);
                issue_coh(hpl + idx, fl[hi2]);
            }
            WAIT16(fh, fl);
#pragma unroll
            for (int hi2 = 0; hi2 < 8; ++hi2) {
                const bf16x8 ahi = __builtin_bit_cast(bf16x8, fh[hi2]);
                const bf16x8 alo = __builtin_bit_cast(bf16x8, fl[hi2]);
                s0[nt] = MFMA(whi[4 + hi2], ahi, s0[nt]);
                s1[nt] = MFMA(whi[4 + hi2], alo, s1[nt]);
                s2[nt] = MFMA(wlo[4 + hi2], ahi, s2[nt]);
            }
        }

        // ---- merge streams + single-phase cross-wave reduction ----
        f32x4 acc[2];
#pragma unroll
        for (int nt = 0; nt < 2; ++nt) acc[nt] = s0[nt] + s1[nt] + s2[nt];
        const int pa = t & 1;

        if (kh != 0) {
#pragma unroll
            for (int nt = 0; nt < 2; ++nt)
#pragma unroll
                for (int i = 0; i < 4; ++i)
                    red[pa][mt][kh - 1][nt][bsub][4 * q + i] = acc[nt][i];
        }
        __syncthreads();

        // ---- gate math (kh==0), h store, ack, publish ----
        if (kh == 0) {
            unsigned short* dsth = hH + ((t + 1) & 1) * HBUF_STRIDE + hblk;
            unsigned short* dstl = hL + ((t + 1) & 1) * HBUF_STRIDE + hblk;
#pragma unroll
            for (int nt = 0; nt < 2; ++nt) {
                float g4[4];
#pragma unroll
                for (int i = 0; i < 4; ++i)
                    g4[i] = acc[nt][i] + bias[i]
                          + red[pa][mt][0][nt][bsub][4 * q + i]
                          + red[pa][mt][1][nt][bsub][4 * q + i]
                          + red[pa][mt][2][nt][bsub][4 * q + i];
                const float ig = fast_sigmoid(g4[0]);
                const float fg = fast_sigmoid(g4[1]);
                const float gg = fast_tanh(g4[2]);
                const float og = fast_sigmoid(g4[3]);
                c[nt] = fg * c[nt] + ig * gg;
                const float h = og * fast_tanh(c[nt]);
                unsigned hi, lo;
                split_bf16(h, hi, lo);
                const int b = bh * 32 + nt * 16 + bsub;
                store_wt_u16(dsth + b * 8 + jlow, (unsigned short)hi);
                store_wt_u16(dstl + b * 8 + jlow, (unsigned short)lo);
                if (t == len[nt] - 1) lasth[nt] = h;
            }
            asm volatile("s_waitcnt vmcnt(0)" ::: "memory");  // h stores visible
            if (l == 0) atomic_add_rlx(prodc);                // publish h_{t+1}
        }
    }

    // ---- epilogue ----
    if (kh == 0) {
#pragma unroll
        for (int nt = 0; nt < 2; ++nt) {
            const int b = bh * 32 + nt * 16 + bsub;
            out[(size_t)b * HH + jcell] = lasth[nt];
        }
    }
}

extern "C" void kernel_launch(void* const* d_in, const int* in_sizes, int n_in,
                              void* d_out, int out_size, void* d_ws, size_t ws_size,
                              hipStream_t stream)
{
    const float* seq  = (const float*)d_in[0];
    const int*   lens = (const int*)  d_in[1];
    const float* Wih  = (const float*)d_in[2];
    const float* Whh  = (const float*)d_in[3];
    const float* bih  = (const float*)d_in[4];
    const float* bhh  = (const float*)d_in[5];
    float* out = (float*)d_out;

    char* ws = (char*)d_ws;
    int*            cnts = (int*)           (ws + WS_CNT_OFF);
    unsigned short* hH   = (unsigned short*)(ws + WS_HPAKH_OFF);
    unsigned short* hL   = (unsigned short*)(ws + WS_HPAKL_OFF);
    unsigned short* xH   = (unsigned short*)(ws + WS_XPAKH_OFF);
    unsigned short* xL   = (unsigned short*)(ws + WS_XPAKL_OFF);

    hipMemsetAsync(cnts, 0, 8192, stream);   // monotonic counters start at 0
    transpose_pack_x<<<dim3(TT), dim3(256), 0, stream>>>(seq, xH, xL);
    lstm_mfma<<<dim3(NBLK), dim3(NTHR), 0, stream>>>(xH, xL, lens, Wih, Whh, bih, bhh,
                                                     hH, hL, cnts, out);
}